// Round 2
// baseline (114.883 us; speedup 1.0000x reference)
//
#include <hip/hip_runtime.h>

#define NBOXES 4096
#define MAX_BS 128
#define INV4PI 0.07957747154594767f
#define CAP 512   // max pairs per u-box; uniform-random 8192 over 4096 -> mean 2, P(>512)~0

// ---------------- Pass B: bin pairs by target (u) box ----------------
__global__ __launch_bounds__(256) void bin_pairs_kernel(
    const int2* __restrict__ uq_boxes, int npairs,
    int* __restrict__ cnt,      // [NBOXES], pre-zeroed
    int* __restrict__ qlist)    // [NBOXES][CAP] source-box ids
{
    int p = blockIdx.x * 256 + threadIdx.x;
    if (p >= npairs) return;
    int2 uq = uq_boxes[p];
    int slot = atomicAdd(&cnt[uq.x], 1);
    if (slot < CAP) qlist[(size_t)uq.x * CAP + slot] = uq.y;
}

// ---------------- Pass C: one block per u-box, gather all its pairs ----------------
__global__ __launch_bounds__(128) void fmm_gather_kernel(
    const float* __restrict__ q_vec,    // [NBOXES][MAX_BS]
    const float* __restrict__ XX,       // [NBOXES][MAX_BS][3]
    const int*   __restrict__ bs_list,  // [NBOXES]
    const int*   __restrict__ cnt,      // [NBOXES]
    const int*   __restrict__ qlist,    // [NBOXES][CAP]
    float*       __restrict__ out)      // [NBOXES][MAX_BS]
{
    const int u = blockIdx.x;
    const int t = threadIdx.x;          // 0..127, target row i = t

    const int bs_u = bs_list[u];
    int npq = cnt[u];
    if (npq > CAP) npq = CAP;

    // Own target point (row t of box u).
    const float* Xu = XX + (size_t)u * (MAX_BS * 3);
    const float xu = Xu[3 * t + 0];
    const float yu = Xu[3 * t + 1];
    const float zu = Xu[3 * t + 2];

    __shared__ float4 sq[MAX_BS];

    const int wbase = t & 64;           // wave's first row (0 or 64)
    float acc = 0.0f;

    for (int k = 0; k < npq; ++k) {
        // q is uniform across the block -> force scalar so address math
        // lands in SGPRs.
        int q = __builtin_amdgcn_readfirstlane(qlist[(size_t)u * CAP + k]);
        const int bs_q = bs_list[q];

        __syncthreads();                // protect LDS from previous iter's readers
        {
            const float* Xq = XX + (size_t)q * (MAX_BS * 3);
            float x = Xq[3 * t + 0];
            float y = Xq[3 * t + 1];
            float z = Xq[3 * t + 2];
            float w = (t < bs_q) ? q_vec[(size_t)q * MAX_BS + t] * INV4PI : 0.0f;
            sq[t] = make_float4(x, y, z, w);
        }
        __syncthreads();

        if (wbase < bs_u) {             // skip waves with no live rows
#pragma unroll 4
            for (int j = 0; j < bs_q; ++j) {
                const float4 s = sq[j];      // wave-uniform addr -> broadcast
                const float dx = xu - s.x;
                const float dy = yu - s.y;
                const float dz = zu - s.z;
                const float r2 = dx * dx + dy * dy + dz * dz;
                float rinv = __builtin_amdgcn_rsqf(r2);
                rinv = (r2 > 0.0f) ? rinv : 0.0f;  // self-interaction -> 0
                acc = fmaf(s.w, rinv, acc);
            }
        }
    }

    // Exactly-once write; dead rows emit 0 (also clears the 0xAA poison).
    out[(size_t)u * MAX_BS + t] = (t < bs_u) ? acc : 0.0f;
}

extern "C" void kernel_launch(void* const* d_in, const int* in_sizes, int n_in,
                              void* d_out, int out_size, void* d_ws, size_t ws_size,
                              hipStream_t stream) {
    const float* q_vec    = (const float*)d_in[0];
    const float* XX_list  = (const float*)d_in[1];
    const int*   bs_list  = (const int*)d_in[2];
    const int2*  uq_boxes = (const int2*)d_in[3];
    float* out = (float*)d_out;

    const int npairs = in_sizes[3] / 2;

    int* cnt   = (int*)d_ws;                 // [NBOXES]
    int* qlist = (int*)d_ws + NBOXES;        // [NBOXES][CAP]

    // Pass A: zero the per-box counters (ws is poisoned 0xAA every iteration).
    hipMemsetAsync(cnt, 0, NBOXES * sizeof(int), stream);

    // Pass B: bin pairs by u.
    bin_pairs_kernel<<<(npairs + 255) / 256, 256, 0, stream>>>(
        uq_boxes, npairs, cnt, qlist);

    // Pass C: gather + write out exactly once (no atomics, no out-memset).
    fmm_gather_kernel<<<NBOXES, 128, 0, stream>>>(
        q_vec, XX_list, bs_list, cnt, qlist, out);
}

// Round 3
// 93.156 us; speedup vs baseline: 1.2332x; 1.2332x over previous
//
#include <hip/hip_runtime.h>

#define NBOXES 4096
#define MAX_BS 128
#define INV4PI 0.07957747154594767f

// Inner loop: one wave sweeps its pair's source list (LDS, broadcast reads),
// computing NR rows (t, t+64) per lane per source point. Chunked x8 so 8
// ds_read_b128 are in flight ahead of dependent VALU.
template<int NR>
__device__ __forceinline__ void sweep(const float4* __restrict__ sq, int bs_q,
                                      const float* xu, const float* yu,
                                      const float* zu, float* acc)
{
    int j = 0;
    for (; j + 8 <= bs_q; j += 8) {
        float4 s[8];
#pragma unroll
        for (int c = 0; c < 8; ++c) s[c] = sq[j + c];
#pragma unroll
        for (int c = 0; c < 8; ++c) {
#pragma unroll
            for (int r = 0; r < NR; ++r) {
                const float dx = xu[r] - s[c].x;
                const float dy = yu[r] - s[c].y;
                const float dz = zu[r] - s[c].z;
                const float r2 = dx * dx + dy * dy + dz * dz;
                float rinv = __builtin_amdgcn_rsqf(r2);
                rinv = (r2 > 0.0f) ? rinv : 0.0f;   // self-interaction -> 0
                acc[r] = fmaf(s[c].w, rinv, acc[r]);
            }
        }
    }
    for (; j < bs_q; ++j) {
        const float4 s = sq[j];
#pragma unroll
        for (int r = 0; r < NR; ++r) {
            const float dx = xu[r] - s.x;
            const float dy = yu[r] - s.y;
            const float dz = zu[r] - s.z;
            const float r2 = dx * dx + dy * dy + dz * dz;
            float rinv = __builtin_amdgcn_rsqf(r2);
            rinv = (r2 > 0.0f) ? rinv : 0.0f;
            acc[r] = fmaf(s.w, rinv, acc[r]);
        }
    }
}

// Block = 128 threads = 2 waves; wave w owns pair (2*blockIdx.x + w).
// Lane t owns target rows t and t+64 of its pair's u box -> one LDS
// broadcast read feeds 2 rows of compute (halves LDS-pipe pressure).
__global__ __launch_bounds__(128) void fmm_pair2_kernel(
    const float* __restrict__ q_vec,    // [NBOXES][MAX_BS]
    const float* __restrict__ XX,       // [NBOXES][MAX_BS][3]
    const int*   __restrict__ bs_list,  // [NBOXES]
    const int2*  __restrict__ uq_boxes, // [NPAIRS]
    int npairs,
    float*       __restrict__ out)      // [NBOXES][MAX_BS]
{
    const int w = threadIdx.x >> 6;       // wave id within block (0/1)
    const int t = threadIdx.x & 63;       // lane
    const int p = blockIdx.x * 2 + w;     // pair id (npairs is even: 8192)

    __shared__ float4 sq[2][MAX_BS];

    const int2 uq = uq_boxes[p];
    const int u = uq.x;
    const int q = uq.y;
    const int bs_u = bs_list[u];
    const int bs_q = bs_list[q];

    // Stage this wave's source box: lane t stages points t and t+64.
    {
        const float* Xq = XX + (size_t)q * (MAX_BS * 3);
        const float* qv = q_vec + (size_t)q * MAX_BS;
#pragma unroll
        for (int r = 0; r < 2; ++r) {
            const int jj = t + 64 * r;
            const float x = Xq[3 * jj + 0];
            const float y = Xq[3 * jj + 1];
            const float z = Xq[3 * jj + 2];
            const float wt = (jj < bs_q) ? qv[jj] * INV4PI : 0.0f;
            sq[w][jj] = make_float4(x, y, z, wt);
        }
    }

    // Own target rows t and t+64.
    const float* Xu = XX + (size_t)u * (MAX_BS * 3);
    float xu[2], yu[2], zu[2];
#pragma unroll
    for (int r = 0; r < 2; ++r) {
        const int ii = t + 64 * r;
        xu[r] = Xu[3 * ii + 0];
        yu[r] = Xu[3 * ii + 1];
        zu[r] = Xu[3 * ii + 2];
    }

    __syncthreads();   // single sync: staging done, waves diverge freely after

    float acc[2] = {0.0f, 0.0f};
    if (bs_u > 64) {                       // wave-uniform row-count gate
        sweep<2>(sq[w], bs_q, xu, yu, zu, acc);
    } else if (bs_u > 0) {
        sweep<1>(sq[w], bs_q, xu, yu, zu, acc);
    }

    float* orow = out + (size_t)u * MAX_BS;
    if (t < bs_u)      atomicAdd(orow + t,      acc[0]);
    if (t + 64 < bs_u) atomicAdd(orow + t + 64, acc[1]);
}

extern "C" void kernel_launch(void* const* d_in, const int* in_sizes, int n_in,
                              void* d_out, int out_size, void* d_ws, size_t ws_size,
                              hipStream_t stream) {
    const float* q_vec    = (const float*)d_in[0];
    const float* XX_list  = (const float*)d_in[1];
    const int*   bs_list  = (const int*)d_in[2];
    const int2*  uq_boxes = (const int2*)d_in[3];
    float* out = (float*)d_out;

    const int npairs = in_sizes[3] / 2;   // 8192 (even)

    // Atomic accumulation needs a zeroed output (harness poisons with 0xAA).
    hipMemsetAsync(d_out, 0, (size_t)out_size * sizeof(float), stream);

    fmm_pair2_kernel<<<npairs / 2, 128, 0, stream>>>(
        q_vec, XX_list, bs_list, uq_boxes, npairs, out);
}

// Round 4
// 92.489 us; speedup vs baseline: 1.2421x; 1.0072x over previous
//
#include <hip/hip_runtime.h>

#define MAX_BS 128
#define INV4PI 0.07957747154594767f
#define GRID 2048   // fully co-resident: 8 blocks/CU x 256 CU

// Persistent-ish: block b handles pairs b, b+GRID, b+2*GRID, ... (4 total).
// Thread i owns target row i of the current pair's u box (exact row masking
// via exec). Source box staged in double-buffered LDS; next pair's setup
// loads are issued before the compute loop so their latency hides behind it.
__global__ __launch_bounds__(128) void fmm_persist_kernel(
    const float* __restrict__ q_vec,    // [NBOXES][MAX_BS]
    const float* __restrict__ XX,       // [NBOXES][MAX_BS][3]
    const int*   __restrict__ bs_list,  // [NBOXES]
    const int2*  __restrict__ uq_boxes, // [NPAIRS]
    int npairs, int iters,
    float*       __restrict__ out)      // [NBOXES][MAX_BS]
{
    const int i = threadIdx.x;          // row / staging index 0..127
    __shared__ float4 sq[2][MAX_BS];

    int p = blockIdx.x;

    // Prologue: raw-load pair p's setup into registers (no compute on the
    // loaded values yet -> no early waitcnt-dependent VALU).
    int u = 0, q = 0, bs_u = 0, bs_q = 0;
    float sx = 0.f, sy = 0.f, sz = 0.f, sw = 0.f;   // source point i of box q
    float xu = 0.f, yu = 0.f, zu = 0.f;             // target point i of box u
    if (p < npairs) {
        const int2 uq = uq_boxes[p];
        u = uq.x; q = uq.y;
        bs_u = bs_list[u]; bs_q = bs_list[q];
        const float* Xq = XX + (size_t)q * (MAX_BS * 3);
        sx = Xq[3 * i + 0]; sy = Xq[3 * i + 1]; sz = Xq[3 * i + 2];
        sw = q_vec[(size_t)q * MAX_BS + i];
        const float* Xu = XX + (size_t)u * (MAX_BS * 3);
        xu = Xu[3 * i + 0]; yu = Xu[3 * i + 1]; zu = Xu[3 * i + 2];
    }

    for (int it = 0; it < iters; ++it) {
        const int buf = it & 1;
        // Stage: apply col mask + INV4PI scale here (value is needed now
        // anyway for the ds_write, so the select costs nothing extra).
        sq[buf][i] = make_float4(sx, sy, sz,
                                 (i < bs_q) ? sw * INV4PI : 0.0f);
        __syncthreads();

        // Snapshot current pair's scalars.
        const int   cu = u, cbs_u = bs_u, cbs_q = bs_q;
        const bool  self  = (u == q);
        const bool  valid = (p < npairs);
        const float cxu = xu, cyu = yu, czu = zu;

        // Prefetch next pair's setup (latency hides behind the j-loop;
        // first use of these registers is next iteration's ds_write).
        p += GRID;
        if (it + 1 < iters && p < npairs) {
            const int2 uq = uq_boxes[p];
            u = uq.x; q = uq.y;
            bs_u = bs_list[u]; bs_q = bs_list[q];
            const float* Xq = XX + (size_t)q * (MAX_BS * 3);
            sx = Xq[3 * i + 0]; sy = Xq[3 * i + 1]; sz = Xq[3 * i + 2];
            sw = q_vec[(size_t)q * MAX_BS + i];
            const float* Xu = XX + (size_t)u * (MAX_BS * 3);
            xu = Xu[3 * i + 0]; yu = Xu[3 * i + 1]; zu = Xu[3 * i + 2];
        }

        // Compute current pair. Rows >= bs_u are exec-masked off (wave 1
        // skips the whole loop via s_cbranch_execz when bs_u <= 64).
        if (valid && i < cbs_u) {
            const float4* __restrict__ s = sq[buf];
            float acc = 0.0f;
            if (self) {
                // u == q (~2 of 8192 pairs): mask exact self-interaction.
#pragma unroll 4
                for (int j = 0; j < cbs_q; ++j) {
                    const float4 sj = s[j];
                    const float dx = cxu - sj.x;
                    const float dy = cyu - sj.y;
                    const float dz = czu - sj.z;
                    const float r2 = dx * dx + dy * dy + dz * dz;
                    float rinv = __builtin_amdgcn_rsqf(r2);
                    rinv = (r2 > 0.0f) ? rinv : 0.0f;
                    acc = fmaf(sj.w, rinv, acc);
                }
            } else {
                // Distinct boxes: r2 > 0 always (random coords), drop the
                // cmp+cndmask -> 8 VALU/iter.
#pragma unroll 4
                for (int j = 0; j < cbs_q; ++j) {
                    const float4 sj = s[j];
                    const float dx = cxu - sj.x;
                    const float dy = cyu - sj.y;
                    const float dz = czu - sj.z;
                    const float r2 = dx * dx + dy * dy + dz * dz;
                    acc = fmaf(sj.w, __builtin_amdgcn_rsqf(r2), acc);
                }
            }
            atomicAdd(out + (size_t)cu * MAX_BS + i, acc);
        }
    }
}

extern "C" void kernel_launch(void* const* d_in, const int* in_sizes, int n_in,
                              void* d_out, int out_size, void* d_ws, size_t ws_size,
                              hipStream_t stream) {
    const float* q_vec    = (const float*)d_in[0];
    const float* XX_list  = (const float*)d_in[1];
    const int*   bs_list  = (const int*)d_in[2];
    const int2*  uq_boxes = (const int2*)d_in[3];
    float* out = (float*)d_out;

    const int npairs = in_sizes[3] / 2;              // 8192
    const int iters  = (npairs + GRID - 1) / GRID;   // 4

    // Atomic accumulation needs a zeroed output (harness poisons with 0xAA).
    hipMemsetAsync(d_out, 0, (size_t)out_size * sizeof(float), stream);

    fmm_persist_kernel<<<GRID, 128, 0, stream>>>(
        q_vec, XX_list, bs_list, uq_boxes, npairs, iters, out);
}

// Round 5
// 85.974 us; speedup vs baseline: 1.3362x; 1.0758x over previous
//
#include <hip/hip_runtime.h>

#define MAX_BS 128
#define INV4PI 0.07957747154594767f

// One block per pair (u,q), 128 threads, thread i = target row i.
// Source box (Xq rows + q_vec) is block-uniform -> read through the SCALAR
// pipe (s_load broadcasts into SGPRs): no LDS, no barrier, no per-iter
// ds_read/waitcnt. Inner loop is 8 pure-VALU ops, each with <=1 SGPR operand.
__global__ __launch_bounds__(128) void fmm_scalar_kernel(
    const float* __restrict__ q_vec,    // [NBOXES][MAX_BS]
    const float* __restrict__ XX,       // [NBOXES][MAX_BS][3]
    const int*   __restrict__ bs_list,  // [NBOXES]
    const int2*  __restrict__ uq_boxes, // [NPAIRS]
    float*       __restrict__ out)      // [NBOXES][MAX_BS]
{
    const int p = blockIdx.x;
    const int t = threadIdx.x;          // target row i

    const int2 uq = uq_boxes[p];
    // Force uniform -> SGPR so all derived addresses are scalar.
    const int u = __builtin_amdgcn_readfirstlane(uq.x);
    const int q = __builtin_amdgcn_readfirstlane(uq.y);
    const int bs_u = bs_list[u];        // uniform -> s_load
    const int bs_q = bs_list[q];

    if (t >= bs_u || bs_q == 0) return; // exact row mask; dead wave exits fast

    // Own target point (vector loads, lane-varying).
    const float* __restrict__ Xu = XX + (size_t)u * (MAX_BS * 3);
    const float xu = Xu[3 * t + 0];
    const float yu = Xu[3 * t + 1];
    const float zu = Xu[3 * t + 2];

    // Uniform source pointers -> scalar loads inside the loop.
    const float* __restrict__ Xq = XX + (size_t)q * (MAX_BS * 3);
    const float* __restrict__ qv = q_vec + (size_t)q * MAX_BS;

    float acc = 0.0f;
    if (u != q) {
        // Distinct boxes: r2 > 0 always (continuous random coords).
#pragma unroll 8
        for (int j = 0; j < bs_q; ++j) {
            const float sx = Xq[3 * j + 0];   // uniform -> s_load, free bcast
            const float sy = Xq[3 * j + 1];
            const float sz = Xq[3 * j + 2];
            const float w  = qv[j];
            const float dx = xu - sx;
            const float dy = yu - sy;
            const float dz = zu - sz;
            const float r2 = dx * dx + dy * dy + dz * dz;
            acc = fmaf(w, __builtin_amdgcn_rsqf(r2), acc);
        }
    } else {
        // Self pair (~2 of 8192): mask exact self-interaction.
#pragma unroll 4
        for (int j = 0; j < bs_q; ++j) {
            const float sx = Xq[3 * j + 0];
            const float sy = Xq[3 * j + 1];
            const float sz = Xq[3 * j + 2];
            const float w  = qv[j];
            const float dx = xu - sx;
            const float dy = yu - sy;
            const float dz = zu - sz;
            const float r2 = dx * dx + dy * dy + dz * dz;
            float rinv = __builtin_amdgcn_rsqf(r2);
            rinv = (r2 > 0.0f) ? rinv : 0.0f;
            acc = fmaf(w, rinv, acc);
        }
    }

    // INV4PI hoisted out of the loop (w was raw q_vec).
    atomicAdd(out + (size_t)u * MAX_BS + t, acc * INV4PI);
}

extern "C" void kernel_launch(void* const* d_in, const int* in_sizes, int n_in,
                              void* d_out, int out_size, void* d_ws, size_t ws_size,
                              hipStream_t stream) {
    const float* q_vec    = (const float*)d_in[0];
    const float* XX_list  = (const float*)d_in[1];
    const int*   bs_list  = (const int*)d_in[2];
    const int2*  uq_boxes = (const int2*)d_in[3];
    float* out = (float*)d_out;

    const int npairs = in_sizes[3] / 2;   // 8192

    // Atomic accumulation needs a zeroed output (harness poisons with 0xAA).
    hipMemsetAsync(d_out, 0, (size_t)out_size * sizeof(float), stream);

    fmm_scalar_kernel<<<npairs, 128, 0, stream>>>(
        q_vec, XX_list, bs_list, uq_boxes, out);
}